// Round 1
// baseline (2182.762 us; speedup 1.0000x reference)
//
#include <hip/hip_runtime.h>

#define NB 128
#define NS 256
#define NI 64
#define NH 128
#define NL 64
#define NG 384  // 3*NH

__device__ __forceinline__ float fast_tanh(float x) {
    // tanh(x) = 1 - 2/(exp(2x)+1); safe at large |x| (exp->inf -> 1, exp->0 -> -1)
    float e = __expf(2.0f * x);
    return 1.0f - 2.0f / (e + 1.0f);
}
__device__ __forceinline__ float fast_sig(float x) {
    return 1.0f / (1.0f + __expf(-x));
}

// ---------------------------------------------------------------------------
// GX precompute: gx[s][b][j] = b_ih[j] + sum_c x[b][s][c] * W_ih[j][c]
// ---------------------------------------------------------------------------
__global__ __launch_bounds__(384)
void gx_kernel(const float* __restrict__ x, const float* __restrict__ W_ih,
               const float* __restrict__ b_ih, float* __restrict__ gx)
{
    const int sb = blockIdx.x;            // s*NB + b
    const int s = sb / NB, b = sb % NB;
    const int j = threadIdx.x;            // 0..383
    __shared__ __align__(16) float xr[NI];
    if (j < NI) xr[j] = x[(b * NS + s) * NI + j];
    __syncthreads();
    const float* wr = W_ih + j * NI;
    float acc = 0.f;
#pragma unroll
    for (int c = 0; c < NI; c += 4) {
        float4 w4 = *(const float4*)(wr + c);
        acc = fmaf(w4.x, xr[c + 0], acc);
        acc = fmaf(w4.y, xr[c + 1], acc);
        acc = fmaf(w4.z, xr[c + 2], acc);
        acc = fmaf(w4.w, xr[c + 3], acc);
    }
    gx[(s * NB + b) * NG + j] = acc + b_ih[j];
}

// ---------------------------------------------------------------------------
// Main persistent recurrence kernel: 1 WG per batch element, 512 threads.
// thread t: row r = t>>2 (0..127), quad p = t&3 handles cols [32p, 32p+32).
// Register-resident weights: w1[32], w2[32], whh{0,1,2}[32].
// ---------------------------------------------------------------------------

#define MATVEC32(W, SRC, ACC)                                                  \
    {                                                                          \
        float a0 = 0.f, a1 = 0.f, a2 = 0.f, a3 = 0.f;                          \
        _Pragma("unroll") for (int j4 = 0; j4 < 8; j4++)                       \
        {                                                                      \
            float4 v4 = *(const float4*)((SRC) + c0 + 4 * j4);                 \
            a0 = fmaf(W[4 * j4 + 0], v4.x, a0);                                \
            a1 = fmaf(W[4 * j4 + 1], v4.y, a1);                                \
            a2 = fmaf(W[4 * j4 + 2], v4.z, a2);                                \
            a3 = fmaf(W[4 * j4 + 3], v4.w, a3);                                \
        }                                                                      \
        ACC = (a0 + a1) + (a2 + a3);                                           \
        ACC += __shfl_xor(ACC, 1);                                             \
        ACC += __shfl_xor(ACC, 2);                                             \
    }

// one ode_f evaluation: k (on p==0 lanes, incl. b2) left in variable KACC
#define ODE_F(IN, KACC)                                                        \
    {                                                                          \
        float accU;                                                            \
        MATVEC32(w1, (IN), accU);                                              \
        if (p == 0) shU[r] = fast_tanh(accU + b1r);                            \
        __syncthreads();                                                       \
        MATVEC32(w2, shU, KACC);                                               \
        KACC += b2r;                                                           \
    }

__global__ __launch_bounds__(512, 2)
void rnn_kernel(const float* __restrict__ times,
                const float* __restrict__ W_hh, const float* __restrict__ b_hh,
                const float* __restrict__ W1, const float* __restrict__ b1,
                const float* __restrict__ W2, const float* __restrict__ b2,
                const float* __restrict__ W_mean, const float* __restrict__ b_mean,
                const float* __restrict__ W_logvar, const float* __restrict__ b_logvar,
                const float* __restrict__ gx,   // [NS][NB][NG] (if use_ws)
                const float* __restrict__ x, const float* __restrict__ W_ih,
                const float* __restrict__ b_ih, // fallback path
                const int use_ws,
                float* __restrict__ out)        // [2][NB][NL]
{
    const int b = blockIdx.x;
    const int t = threadIdx.x;
    const int r = t >> 2;
    const int p = t & 3;
    const int c0 = 32 * p;

    __shared__ __align__(16) float shA[NH], shB[NH], shV[NH], shU[NH], shK[NH];
    __shared__ float shT[NS];
    __shared__ float shGX[NG];
    __shared__ float shX[NI];

    // ---- register-resident weights (static indexing only!) ----
    float w1[32], w2[32], whh0[32], whh1[32], whh2[32];
#pragma unroll
    for (int j = 0; j < 32; j++) {
        w1[j]   = W1[r * NH + c0 + j];
        w2[j]   = W2[r * NH + c0 + j];
        whh0[j] = W_hh[(0 * NH + r) * NH + c0 + j];
        whh1[j] = W_hh[(1 * NH + r) * NH + c0 + j];
        whh2[j] = W_hh[(2 * NH + r) * NH + c0 + j];
    }
    const float b1r = b1[r], b2r = b2[r];
    const float bh0 = b_hh[r], bh1 = b_hh[NH + r], bh2 = b_hh[2 * NH + r];

    if (t < NS) shT[t] = times[t];
    if (t < NH) shA[t] = 0.f;
    __syncthreads();

    for (int si = 0; si < NS; ++si) {
        const int seq = NS - 1 - si;
        const float dt = (si == 0) ? 0.f : (shT[seq] - shT[seq + 1]);
        const float dtS = 0.5f * dt;        // per-substep dt (N_SUB = 2)
        const float half = 0.5f * dtS;

        // prefetch this step's gx early (hides HBM/L2 latency under the ode work)
        float gxr = 0.f, gxz = 0.f, gxn = 0.f;
        if (use_ws) {
            if (p == 0) {
                const float* g = gx + ((size_t)seq * NB + b) * NG;
                gxr = g[r];
                gxz = g[NH + r];
                gxn = g[2 * NH + r];
            }
        } else {
            // fallback: compute gx into LDS from global W_ih
            if (t < NI) shX[t] = x[(b * NS + seq) * NI + t];
            __syncthreads();
            if (t < NG) {
                const float* wr = W_ih + t * NI;
                float a = 0.f;
#pragma unroll
                for (int cc = 0; cc < NI; cc += 4) {
                    float4 w4 = *(const float4*)(wr + cc);
                    a = fmaf(w4.x, shX[cc + 0], a);
                    a = fmaf(w4.y, shX[cc + 1], a);
                    a = fmaf(w4.z, shX[cc + 2], a);
                    a = fmaf(w4.w, shX[cc + 3], a);
                }
                shGX[t] = a + b_ih[t];
            }
            __syncthreads();
        }

        float* hcur = (si & 1) ? shB : shA;
        float* hnew = (si & 1) ? shA : shB;

        // ---- two RK4 substeps (in-place on hcur; element-wise ownership) ----
#pragma unroll 1
        for (int ss = 0; ss < 2; ++ss) {
            float k;
            // stage 1: k1 = f(h)
            ODE_F(hcur, k);
            if (p == 0) {
                shK[r] = k;
                shV[r] = hcur[r] + half * k;
            }
            __syncthreads();
            // stage 2: k2 = f(h + half*k1)
            ODE_F(shV, k);
            if (p == 0) {
                shK[r] += 2.f * k;
                shV[r] = hcur[r] + half * k;
            }
            __syncthreads();
            // stage 3: k3 = f(h + half*k2)
            ODE_F(shV, k);
            if (p == 0) {
                shK[r] += 2.f * k;
                shV[r] = hcur[r] + dtS * k;
            }
            __syncthreads();
            // stage 4: k4 = f(h + dtS*k3);  h += dtS/6*(k1+2k2+2k3+k4)
            ODE_F(shV, k);
            if (p == 0) {
                hcur[r] = hcur[r] + (dtS * (1.f / 6.f)) * (shK[r] + k);
            }
            __syncthreads();
        }

        // ---- GRU cell: gh = h @ W_hh^T (3 gates fused over one h read) ----
        float g0 = 0.f, g1 = 0.f, g2 = 0.f;
        {
            float a00 = 0.f, a10 = 0.f, a20 = 0.f;
            float a01 = 0.f, a11 = 0.f, a21 = 0.f;
#pragma unroll
            for (int j4 = 0; j4 < 8; j4++) {
                float4 v4 = *(const float4*)(hcur + c0 + 4 * j4);
                a00 = fmaf(whh0[4 * j4 + 0], v4.x, a00);
                a01 = fmaf(whh0[4 * j4 + 1], v4.y, a01);
                a00 = fmaf(whh0[4 * j4 + 2], v4.z, a00);
                a01 = fmaf(whh0[4 * j4 + 3], v4.w, a01);
                a10 = fmaf(whh1[4 * j4 + 0], v4.x, a10);
                a11 = fmaf(whh1[4 * j4 + 1], v4.y, a11);
                a10 = fmaf(whh1[4 * j4 + 2], v4.z, a10);
                a11 = fmaf(whh1[4 * j4 + 3], v4.w, a11);
                a20 = fmaf(whh2[4 * j4 + 0], v4.x, a20);
                a21 = fmaf(whh2[4 * j4 + 1], v4.y, a21);
                a20 = fmaf(whh2[4 * j4 + 2], v4.z, a20);
                a21 = fmaf(whh2[4 * j4 + 3], v4.w, a21);
            }
            g0 = a00 + a01; g1 = a10 + a11; g2 = a20 + a21;
            g0 += __shfl_xor(g0, 1); g0 += __shfl_xor(g0, 2);
            g1 += __shfl_xor(g1, 1); g1 += __shfl_xor(g1, 2);
            g2 += __shfl_xor(g2, 1); g2 += __shfl_xor(g2, 2);
        }
        if (p == 0) {
            float rx, zx, nx;
            if (use_ws) {
                rx = gxr; zx = gxz; nx = gxn;
            } else {
                rx = shGX[r]; zx = shGX[NH + r]; nx = shGX[2 * NH + r];
            }
            float rr = fast_sig(rx + g0 + bh0);
            float zz = fast_sig(zx + g1 + bh1);
            float nn = fast_tanh(nx + rr * (g2 + bh2));
            hnew[r] = (1.f - zz) * nn + zz * hcur[r];
        }
        __syncthreads();
    }

    // ---- epilogue: mean = h@W_mean^T + b_mean ; logvar likewise ----
    const float* hf = (NS & 1) ? shB : shA;  // NS=256 even -> final h in shA
    const int sel = r >> 6;                  // 0: mean rows, 1: logvar rows
    const int l = r & 63;
    const float* Wf = sel ? W_logvar : W_mean;
    float acc;
    {
        float a0 = 0.f, a1 = 0.f, a2 = 0.f, a3 = 0.f;
#pragma unroll
        for (int j4 = 0; j4 < 8; j4++) {
            float4 w4 = *(const float4*)(Wf + l * NH + c0 + 4 * j4);
            float4 h4 = *(const float4*)(hf + c0 + 4 * j4);
            a0 = fmaf(w4.x, h4.x, a0);
            a1 = fmaf(w4.y, h4.y, a1);
            a2 = fmaf(w4.z, h4.z, a2);
            a3 = fmaf(w4.w, h4.w, a3);
        }
        acc = (a0 + a1) + (a2 + a3);
        acc += __shfl_xor(acc, 1);
        acc += __shfl_xor(acc, 2);
    }
    if (p == 0) {
        const float bias = sel ? b_logvar[l] : b_mean[l];
        out[sel * (NB * NL) + b * NL + l] = acc + bias;
    }
}

extern "C" void kernel_launch(void* const* d_in, const int* in_sizes, int n_in,
                              void* d_out, int out_size, void* d_ws, size_t ws_size,
                              hipStream_t stream)
{
    const float* x        = (const float*)d_in[0];
    const float* times    = (const float*)d_in[1];
    const float* W_ih     = (const float*)d_in[2];
    const float* W_hh     = (const float*)d_in[3];
    const float* b_ih     = (const float*)d_in[4];
    const float* b_hh     = (const float*)d_in[5];
    const float* W1       = (const float*)d_in[6];
    const float* b1       = (const float*)d_in[7];
    const float* W2       = (const float*)d_in[8];
    const float* b2       = (const float*)d_in[9];
    const float* W_mean   = (const float*)d_in[10];
    const float* b_mean   = (const float*)d_in[11];
    const float* W_logvar = (const float*)d_in[12];
    const float* b_logvar = (const float*)d_in[13];
    float* out = (float*)d_out;

    const size_t need = (size_t)NS * NB * NG * sizeof(float);  // ~50.3 MB
    const int use_ws = (d_ws != nullptr && ws_size >= need) ? 1 : 0;
    float* gxbuf = (float*)d_ws;

    if (use_ws) {
        gx_kernel<<<NS * NB, 384, 0, stream>>>(x, W_ih, b_ih, gxbuf);
    }
    rnn_kernel<<<NB, 512, 0, stream>>>(times, W_hh, b_hh, W1, b1, W2, b2,
                                       W_mean, b_mean, W_logvar, b_logvar,
                                       gxbuf, x, W_ih, b_ih, use_ws, out);
}